// Round 11
// baseline (41.979 us; speedup 1.0000x reference)
//
#include <hip/hip_runtime.h>

// RNN(tanh) fused forward — v8: minimize consumer transcendental issue.
// Consumer trans ops 5/step -> 3/step: joint-rcp (one rcp for both tanh
// denominators, exact) + output exp2 offloaded to producer (R5 split,
// the only change the R4-R10 plateau ever responded to), now at 2
// blocks/CU so blocks' phases interleave.
// 512 blocks x 128 threads. wave0 = consumer (recurrence, LDS-only).
// wave1 = producer (global_load_lds x staging + out-stream exp2 + NT store).

#define T_STEPS 512
#define BATCH   32768
#define CH      32              // timesteps per chunk
#define NCH     (T_STEPS / CH)  // 16 chunks

typedef float v2f __attribute__((ext_vector_type(2)));

__global__ __launch_bounds__(128) void rnn_v8_kernel(
    const v2f*   __restrict__ x,     // [T][B] float2
    const float* __restrict__ W_ih,  // [2][2]
    const float* __restrict__ W_hh,  // [2][2]
    const float* __restrict__ b_ih,  // [2]
    const float* __restrict__ b_hh,  // [2]
    const float* __restrict__ fc_w,  // [1][2]
    const float* __restrict__ fc_b,  // [1]
    float*       __restrict__ out)   // [T*B] output, then [B][2] h_last
{
    __shared__ v2f xbuf[2][CH][64];   // 32KB x double buffer
    __shared__ v2f hbuf[2][CH][64];   // 32KB h double buffer

    const int tid  = threadIdx.x;
    const int wave = tid >> 6;
    const int lane = tid & 63;
    const size_t bbase = (size_t)blockIdx.x * 64;

    const float L2E = 1.44269504088896340736f;   // log2(e)

    if (wave == 1) {
        // ---------------- producer: x DMA + output stream ----------------
        const float f0 = fc_w[0]*L2E, f1 = fc_w[1]*L2E, fb = fc_b[0]*L2E;
        float* op = out + bbase + lane;

        // one gload_lds covers 2 rows (64 lanes x 16B = 1KB; row = 512B)
        const int rofs = lane >> 5;
        const int cofs = (lane & 31) * 2;

        // prologue: chunk 0 -> slot 0
        #pragma unroll
        for (int k = 0; k < CH / 2; ++k) {
            const v2f* src = x + (size_t)(2 * k + rofs) * BATCH + bbase + cofs;
            __builtin_amdgcn_global_load_lds(
                (const __attribute__((address_space(1))) void*)src,
                (__attribute__((address_space(3))) void*)(&xbuf[0][2 * k][0] + lane * 2),
                16, 0, 0);
        }
        __syncthreads();

        for (int c = 0; c < NCH; ++c) {
            // (a) DMA chunk c+1 (issue first: stays in flight under (b))
            if (c + 1 < NCH) {
                const size_t t0 = (size_t)(c + 1) * CH;
                #pragma unroll
                for (int k = 0; k < CH / 2; ++k) {
                    const v2f* src = x + (t0 + 2 * k + rofs) * BATCH + bbase + cofs;
                    __builtin_amdgcn_global_load_lds(
                        (const __attribute__((address_space(1))) void*)src,
                        (__attribute__((address_space(3))) void*)(&xbuf[(c + 1) & 1][2 * k][0] + lane * 2),
                        16, 0, 0);
                }
            }
            // (b) output stream for chunk c-1 from the h ring
            if (c > 0) {
                const int tb = (c - 1) * CH;
                #pragma unroll
                for (int i = 0; i < CH; ++i) {
                    const v2f hv = hbuf[(c - 1) & 1][i][lane];
                    const float z = fmaf(hv.x, f0, fmaf(hv.y, f1, fb));
                    __builtin_nontemporal_store(__builtin_amdgcn_exp2f(z),
                                                &op[(size_t)(tb + i) * BATCH]);
                }
            }
            __syncthreads();
        }
        // epilogue: output stream for the final chunk
        {
            const int tb = (NCH - 1) * CH;
            #pragma unroll
            for (int i = 0; i < CH; ++i) {
                const v2f hv = hbuf[(NCH - 1) & 1][i][lane];
                const float z = fmaf(hv.x, f0, fmaf(hv.y, f1, fb));
                __builtin_nontemporal_store(__builtin_amdgcn_exp2f(z),
                                            &op[(size_t)(tb + i) * BATCH]);
            }
        }
    } else {
        // ---------------- consumer: recurrence only ----------------
        const float S = 2.0f * L2E;  // pre-scale: a' = 2*log2e*a feeds exp2
        const float w00 = W_ih[0]*S, w01 = W_ih[1]*S, w10 = W_ih[2]*S, w11 = W_ih[3]*S;
        const float u00 = W_hh[0]*S, u01 = W_hh[1]*S, u10 = W_hh[2]*S, u11 = W_hh[3]*S;
        const float bi0 = (b_ih[0] + b_hh[0])*S, bi1 = (b_ih[1] + b_hh[1])*S;

        float h0 = 0.0f, h1 = 0.0f;

        __syncthreads();   // matches producer prologue barrier

        for (int c = 0; c < NCH; ++c) {
            // batch ALL x-reads of the chunk into registers
            v2f xr[CH];
            #pragma unroll
            for (int i = 0; i < CH; ++i)
                xr[i] = xbuf[c & 1][i][lane];

            #pragma unroll
            for (int i = 0; i < CH; ++i) {
                float a0 = fmaf(xr[i].x, w00, fmaf(xr[i].y, w01, bi0));
                float a1 = fmaf(xr[i].x, w10, fmaf(xr[i].y, w11, bi1));
                a0 = fmaf(h1, u01, a0);  a0 = fmaf(h0, u00, a0);
                a1 = fmaf(h0, u10, a1);  a1 = fmaf(h1, u11, a1);

                // tanh pair with ONE reciprocal (exact):
                // h_k = 1 - 2/(e_k+1);  r = 1/((e0+1)(e1+1))
                const float e0 = __builtin_amdgcn_exp2f(a0);
                const float e1 = __builtin_amdgcn_exp2f(a1);
                const float s0 = e0 + 1.0f;
                const float s1 = e1 + 1.0f;
                const float r  = __builtin_amdgcn_rcpf(s0 * s1);
                h0 = fmaf(-2.0f * s1, r, 1.0f);
                h1 = fmaf(-2.0f * s0, r, 1.0f);

                v2f hv; hv.x = h0; hv.y = h1;
                hbuf[c & 1][i][lane] = hv;
            }
            __syncthreads();
        }

        // h_last: [1][B][2] — one 8B store per lane
        v2f hv; hv.x = h0; hv.y = h1;
        __builtin_nontemporal_store(hv, (v2f*)(out + (size_t)T_STEPS * BATCH) + bbase + lane);
    }
}

extern "C" void kernel_launch(void* const* d_in, const int* in_sizes, int n_in,
                              void* d_out, int out_size, void* d_ws, size_t ws_size,
                              hipStream_t stream) {
    const v2f*   x    = (const v2f*)d_in[0];
    const float* W_ih = (const float*)d_in[1];
    const float* W_hh = (const float*)d_in[2];
    const float* b_ih = (const float*)d_in[3];
    const float* b_hh = (const float*)d_in[4];
    const float* fc_w = (const float*)d_in[5];
    const float* fc_b = (const float*)d_in[6];
    float* out = (float*)d_out;

    rnn_v8_kernel<<<dim3(BATCH / 64), dim3(128), 0, stream>>>(
        x, W_ih, W_hh, b_ih, b_hh, fc_w, fc_b, out);
}

// Round 12
// 41.783 us; speedup vs baseline: 1.0047x; 1.0047x over previous
//
#include <hip/hip_runtime.h>

// RNN(tanh) fused forward — v9: transaction-width build on the R5 skeleton.
// T=512, B=32768, H=2. 256 blocks x 192 threads, 128 chains/block, 1 block/CU.
// waves 0-1: consumers, 1 chain/lane, recurrence with joint-rcp tanh,
//   h -> LDS ring only (no global traffic).
// wave 2: producer. x staging = ONE global_load_lds(16B) per row (1KB
//   contiguous burst). Output stream = 2 chains/lane: ds_read_b128 h-pair,
//   2x exp2, ONE float2 (8B) NT store -> 512B/wave store bursts (vs 256B).

#define T_STEPS 512
#define BATCH   32768
#define CH      32              // timesteps per chunk
#define NCH     (T_STEPS / CH)  // 16 chunks
#define CPB     128             // chains per block

typedef float v2f __attribute__((ext_vector_type(2)));
typedef float v4f __attribute__((ext_vector_type(4)));

__global__ __launch_bounds__(192) void rnn_v9_kernel(
    const v2f*   __restrict__ x,     // [T][B] float2
    const float* __restrict__ W_ih,  // [2][2]
    const float* __restrict__ W_hh,  // [2][2]
    const float* __restrict__ b_ih,  // [2]
    const float* __restrict__ b_hh,  // [2]
    const float* __restrict__ fc_w,  // [1][2]
    const float* __restrict__ fc_b,  // [1]
    float*       __restrict__ out)   // [T*B] output, then [B][2] h_last
{
    __shared__ v2f xbuf[2][CH][CPB];   // 64KB x double buffer
    __shared__ v2f hbuf[2][CH][CPB];   // 64KB h double buffer

    const int tid  = threadIdx.x;
    const int wave = tid >> 6;
    const int lane = tid & 63;
    const size_t bbase = (size_t)blockIdx.x * CPB;

    const float L2E = 1.44269504088896340736f;   // log2(e)

    if (wave == 2) {
        // ---------------- producer: x DMA + output stream ----------------
        const float f0 = fc_w[0]*L2E, f1 = fc_w[1]*L2E, fb = fc_b[0]*L2E;
        // output: 2 chains per lane -> float2 store at chains (2*lane, 2*lane+1)
        v2f* opv = (v2f*)(out + bbase) + lane;   // 8B-aligned (bbase even)

        // prologue: chunk 0 -> slot 0 (one 1KB DMA per row)
        #pragma unroll
        for (int i = 0; i < CH; ++i) {
            const v2f* src = x + (size_t)i * BATCH + bbase + lane * 2;
            __builtin_amdgcn_global_load_lds(
                (const __attribute__((address_space(1))) void*)src,
                (__attribute__((address_space(3))) void*)&xbuf[0][i][0],
                16, 0, 0);
        }
        __syncthreads();

        for (int c = 0; c < NCH; ++c) {
            // (a) DMA chunk c+1 (issued first, in flight under (b))
            if (c + 1 < NCH) {
                const size_t t0 = (size_t)(c + 1) * CH;
                #pragma unroll
                for (int i = 0; i < CH; ++i) {
                    const v2f* src = x + (t0 + i) * BATCH + bbase + lane * 2;
                    __builtin_amdgcn_global_load_lds(
                        (const __attribute__((address_space(1))) void*)src,
                        (__attribute__((address_space(3))) void*)&xbuf[(c + 1) & 1][i][0],
                        16, 0, 0);
                }
            }
            // (b) output stream for chunk c-1: h-pair -> exp2 -> 8B NT store
            if (c > 0) {
                const int tb = (c - 1) * CH;
                #pragma unroll
                for (int i = 0; i < CH; ++i) {
                    const v4f hp = *(const v4f*)&hbuf[(c - 1) & 1][i][lane * 2];
                    const float zA = fmaf(hp.x, f0, fmaf(hp.y, f1, fb));
                    const float zB = fmaf(hp.z, f0, fmaf(hp.w, f1, fb));
                    v2f zo; zo.x = __builtin_amdgcn_exp2f(zA);
                    zo.y = __builtin_amdgcn_exp2f(zB);
                    __builtin_nontemporal_store(zo, &opv[(size_t)(tb + i) * (BATCH / 2)]);
                }
            }
            __syncthreads();
        }
        // epilogue: output stream for the final chunk
        {
            const int tb = (NCH - 1) * CH;
            #pragma unroll
            for (int i = 0; i < CH; ++i) {
                const v4f hp = *(const v4f*)&hbuf[(NCH - 1) & 1][i][lane * 2];
                const float zA = fmaf(hp.x, f0, fmaf(hp.y, f1, fb));
                const float zB = fmaf(hp.z, f0, fmaf(hp.w, f1, fb));
                v2f zo; zo.x = __builtin_amdgcn_exp2f(zA);
                zo.y = __builtin_amdgcn_exp2f(zB);
                __builtin_nontemporal_store(zo, &opv[(size_t)(tb + i) * (BATCH / 2)]);
            }
        }
    } else {
        // ---------------- consumers (waves 0,1): recurrence only ----------------
        const float S = 2.0f * L2E;  // pre-scale: a' = 2*log2e*a feeds exp2
        const float w00 = W_ih[0]*S, w01 = W_ih[1]*S, w10 = W_ih[2]*S, w11 = W_ih[3]*S;
        const float u00 = W_hh[0]*S, u01 = W_hh[1]*S, u10 = W_hh[2]*S, u11 = W_hh[3]*S;
        const float bi0 = (b_ih[0] + b_hh[0])*S, bi1 = (b_ih[1] + b_hh[1])*S;

        const int j = (wave << 6) + lane;   // chain within block (0..127)
        float h0 = 0.0f, h1 = 0.0f;

        __syncthreads();   // matches producer prologue barrier

        for (int c = 0; c < NCH; ++c) {
            // batch ALL x-reads of the chunk into registers
            v2f xr[CH];
            #pragma unroll
            for (int i = 0; i < CH; ++i)
                xr[i] = xbuf[c & 1][i][j];

            #pragma unroll
            for (int i = 0; i < CH; ++i) {
                float a0 = fmaf(xr[i].x, w00, fmaf(xr[i].y, w01, bi0));
                float a1 = fmaf(xr[i].x, w10, fmaf(xr[i].y, w11, bi1));
                a0 = fmaf(h1, u01, a0);  a0 = fmaf(h0, u00, a0);
                a1 = fmaf(h0, u10, a1);  a1 = fmaf(h1, u11, a1);

                // tanh pair with ONE reciprocal (exact):
                const float e0 = __builtin_amdgcn_exp2f(a0);
                const float e1 = __builtin_amdgcn_exp2f(a1);
                const float s0 = e0 + 1.0f;
                const float s1 = e1 + 1.0f;
                const float r  = __builtin_amdgcn_rcpf(s0 * s1);
                h0 = fmaf(-2.0f * s1, r, 1.0f);
                h1 = fmaf(-2.0f * s0, r, 1.0f);

                v2f hv; hv.x = h0; hv.y = h1;
                hbuf[c & 1][i][j] = hv;
            }
            __syncthreads();
        }

        // h_last: [1][B][2] — one 8B store per lane
        v2f hv; hv.x = h0; hv.y = h1;
        __builtin_nontemporal_store(hv, (v2f*)(out + (size_t)T_STEPS * BATCH) + bbase + j);
    }
}

extern "C" void kernel_launch(void* const* d_in, const int* in_sizes, int n_in,
                              void* d_out, int out_size, void* d_ws, size_t ws_size,
                              hipStream_t stream) {
    const v2f*   x    = (const v2f*)d_in[0];
    const float* W_ih = (const float*)d_in[1];
    const float* W_hh = (const float*)d_in[2];
    const float* b_ih = (const float*)d_in[3];
    const float* b_hh = (const float*)d_in[4];
    const float* fc_w = (const float*)d_in[5];
    const float* fc_b = (const float*)d_in[6];
    float* out = (float*)d_out;

    rnn_v9_kernel<<<dim3(BATCH / CPB), dim3(192), 0, stream>>>(
        x, W_ih, W_hh, b_ih, b_hh, fc_w, fc_b, out);
}